// Round 1
// baseline (196.252 us; speedup 1.0000x reference)
//
#include <hip/hip_runtime.h>

typedef _Float16 half_t;
typedef _Float16 half8 __attribute__((ext_vector_type(8)));
typedef float f32x4 __attribute__((ext_vector_type(4)));

static_assert(sizeof(half8) == 16, "half8 must be 16B");

__device__ inline half8 make_h8(unsigned long lo, unsigned long hi) {
  union { half8 v; unsigned long u[2]; } x;
  x.u[0] = lo; x.u[1] = hi;
  return x.v;
}

__device__ inline void gload_lds16(const void* g, void* l) {
  __builtin_amdgcn_global_load_lds(
      (const __attribute__((address_space(1))) unsigned int*)g,
      (__attribute__((address_space(3))) unsigned int*)l, 16, 0, 0);
}

// x [b][c=512][s=1024] f32  ->  xr [b][s][c] f16   (LDS tile transpose)
__global__ void prep_x_kernel(const float* __restrict__ x, half_t* __restrict__ xr) {
  __shared__ float t[32][33];
  const int b = blockIdx.z;
  const int c0 = blockIdx.y * 32;
  const int s0 = blockIdx.x * 32;
  const int tx = threadIdx.x, ty = threadIdx.y;  // 32 x 8
  const float* xp = x + ((size_t)b * 512 + c0) * 1024 + s0;
#pragma unroll
  for (int r = 0; r < 4; r++) {
    const int cl = ty + 8 * r;
    t[cl][tx] = xp[(size_t)cl * 1024 + tx];
  }
  __syncthreads();
  half_t* op = xr + ((size_t)b * 1024 + s0) * 512 + c0;
#pragma unroll
  for (int r = 0; r < 4; r++) {
    const int sl = ty + 8 * r;
    op[(size_t)sl * 512 + tx] = (half_t)t[tx][sl];
  }
}

// Convert 4 weight matrices [512][512] f32 -> f16 (layout preserved, K-contiguous)
__global__ void prep_w_kernel(const float* __restrict__ w0, const float* __restrict__ w1,
                              const float* __restrict__ w2, const float* __restrict__ w3,
                              half_t* __restrict__ out) {
  const int mz = blockIdx.y;
  const float* src = (mz == 0) ? w0 : (mz == 1) ? w1 : (mz == 2) ? w2 : w3;
  const int i = blockIdx.x * 256 + threadIdx.x;
  const float4 v = ((const float4*)src)[i];
  half_t* o = out + (size_t)mz * 262144 + (size_t)i * 4;
  o[0] = (half_t)v.x; o[1] = (half_t)v.y; o[2] = (half_t)v.z; o[3] = (half_t)v.w;
}

// C[m][n] = sum_k A[m][k] * W[n][k] + bias[n]
// MODE 0: A = xr, W = {Wq,Wk,Wv}[z], out f16 scattered to Q/K/V [b][h][s][64]
// MODE 1: A = attn_out, W = Wo, out f32 row-major to d_out
template <int MODE>
__global__ __launch_bounds__(256, 2) void gemm_kernel(
    const half_t* __restrict__ A, const half_t* __restrict__ Wall,
    const float* __restrict__ b0, const float* __restrict__ b1,
    const float* __restrict__ b2, half_t* __restrict__ qkv,
    float* __restrict__ fout) {
  constexpr int K = 512;
  __shared__ alignas(16) half_t lA[128 * 64];
  __shared__ alignas(16) half_t lB[128 * 64];

  const int z = blockIdx.z;
  const half_t* W = Wall + (size_t)z * K * 512;
  const float* bias = (MODE == 1) ? b0 : (z == 0 ? b0 : (z == 1 ? b1 : b2));

  const int tid = threadIdx.x;
  const int lane = tid & 63;
  const int wid = tid >> 6;
  const int wm = wid >> 1, wn = wid & 1;       // 2x2 waves, each 64x64
  const int g = lane >> 4, r16 = lane & 15;
  const int m0 = blockIdx.y * 128, n0 = blockIdx.x * 128;

  f32x4 acc[4][4];
#pragma unroll
  for (int i = 0; i < 4; i++)
#pragma unroll
    for (int j = 0; j < 4; j++) acc[i][j] = (f32x4){0.f, 0.f, 0.f, 0.f};

  for (int k0 = 0; k0 < K; k0 += 64) {
    // stage A[128][64] and B[128][64] f16 tiles; LDS linear, source pre-swizzled
    // so that LDS[row][kb] = A[row][kb ^ ((row&7)<<4)]  (16B-granular XOR)
#pragma unroll
    for (int t = 0; t < 4; t++) {
      const int o = (t * 256 + tid) * 16;  // byte offset in 16KB tile
      const int row = o >> 7;
      const int kb = o & 127;
      const int kbs = kb ^ ((row & 7) << 4);
      gload_lds16((const char*)(A + (size_t)(m0 + row) * K + k0) + kbs, (char*)lA + o);
      gload_lds16((const char*)(W + (size_t)(n0 + row) * K + k0) + kbs, (char*)lB + o);
    }
    __syncthreads();
#pragma unroll
    for (int kk = 0; kk < 2; kk++) {
      half8 af[4], bf[4];
#pragma unroll
      for (int i = 0; i < 4; i++) {
        const int row = wm * 64 + i * 16 + r16;
        const int sw = (row & 7) << 4;
        const char* p = (const char*)lA + row * 128;
        af[i] = make_h8(*(const unsigned long*)(p + ((kk * 64 + g * 8) ^ sw)),
                        *(const unsigned long*)(p + ((kk * 64 + 32 + g * 8) ^ sw)));
      }
#pragma unroll
      for (int j = 0; j < 4; j++) {
        const int row = wn * 64 + j * 16 + r16;
        const int sw = (row & 7) << 4;
        const char* p = (const char*)lB + row * 128;
        bf[j] = make_h8(*(const unsigned long*)(p + ((kk * 64 + g * 8) ^ sw)),
                        *(const unsigned long*)(p + ((kk * 64 + 32 + g * 8) ^ sw)));
      }
#pragma unroll
      for (int i = 0; i < 4; i++)
#pragma unroll
        for (int j = 0; j < 4; j++)
          acc[i][j] = __builtin_amdgcn_mfma_f32_16x16x32_f16(af[i], bf[j], acc[i][j], 0, 0, 0);
    }
    __syncthreads();
  }

  half_t* dst = (MODE == 0) ? (qkv + (size_t)z * 4194304) : (half_t*)nullptr;
#pragma unroll
  for (int i = 0; i < 4; i++) {
#pragma unroll
    for (int j = 0; j < 4; j++) {
      const int n = n0 + wn * 64 + j * 16 + r16;
      const float bvv = bias[n];
#pragma unroll
      for (int rr = 0; rr < 4; rr++) {
        const int m = m0 + wm * 64 + i * 16 + g * 4 + rr;
        const float v = acc[i][j][rr] + bvv;
        if (MODE == 0) {
          const int bb = m >> 10, s = m & 1023, hh = n >> 6, d = n & 63;
          dst[(((size_t)(bb * 8 + hh) * 1024 + s) << 6) + d] = (half_t)v;
        } else {
          fout[(size_t)m * 512 + n] = v;
        }
      }
    }
  }
}

// Flash attention, one 16-row Q tile per wave, swapped QK^T (S^T = K*Q^T) so the
// P tile stays lane-local between softmax and PV.  O[b][s][h*64+d] f16.
__global__ __launch_bounds__(256) void attn_kernel(
    const half_t* __restrict__ Q, const half_t* __restrict__ Kh,
    const half_t* __restrict__ V, half_t* __restrict__ O) {
  const int tid = threadIdx.x;
  const int lane = tid & 63;
  const int w = blockIdx.x * 4 + (tid >> 6);
  const int bh = w >> 6, qt = w & 63;
  const int b = bh >> 3, h = bh & 7;
  const int g = lane >> 4, r16 = lane & 15;

  const size_t base = (size_t)bh * 65536;  // 1024*64
  const half_t* Qp = Q + base;
  const half_t* Kp = Kh + base;
  const half_t* Vp = V + base;
  const int q0 = qt * 16;

  // Q fragments (B operand): lane holds q-row r16, k elems c = kk*32 + g*4+j+16h
  half8 qf[2];
  {
    const half_t* qrow = Qp + (size_t)(q0 + r16) * 64;
#pragma unroll
    for (int kk = 0; kk < 2; kk++)
      qf[kk] = make_h8(*(const unsigned long*)(qrow + kk * 32 + g * 4),
                       *(const unsigned long*)(qrow + kk * 32 + g * 4 + 16));
  }

  f32x4 acc[4];  // O^T accumulator: 4 d-tiles x (rows g*4+rr), col q=r16
#pragma unroll
  for (int i = 0; i < 4; i++) acc[i] = (f32x4){0.f, 0.f, 0.f, 0.f};
  float mrun = -1e30f, lrun = 0.f;

  for (int kv0 = 0; kv0 < 1024; kv0 += 32) {
    // S^T[kv][q]: D0 = kv rows kv0+0..15, D1 = kv0+16..31
    f32x4 s0 = {0.f, 0.f, 0.f, 0.f}, s1 = {0.f, 0.f, 0.f, 0.f};
#pragma unroll
    for (int kk = 0; kk < 2; kk++) {
      const half_t* kr = Kp + (size_t)(kv0 + r16) * 64 + kk * 32 + g * 4;
      half8 k0 = make_h8(*(const unsigned long*)(kr), *(const unsigned long*)(kr + 16));
      half8 k1 = make_h8(*(const unsigned long*)(kr + 1024), *(const unsigned long*)(kr + 1040));
      s0 = __builtin_amdgcn_mfma_f32_16x16x32_f16(k0, qf[kk], s0, 0, 0, 0);
      s1 = __builtin_amdgcn_mfma_f32_16x16x32_f16(k1, qf[kk], s1, 0, 0, 0);
    }
    // online softmax over this lane's 8 kv entries + cross-group reduce
    float p[8];
#pragma unroll
    for (int i = 0; i < 4; i++) { p[i] = s0[i] * 0.125f; p[4 + i] = s1[i] * 0.125f; }
    float tmax = p[0];
#pragma unroll
    for (int i = 1; i < 8; i++) tmax = fmaxf(tmax, p[i]);
    tmax = fmaxf(tmax, __shfl_xor(tmax, 16));
    tmax = fmaxf(tmax, __shfl_xor(tmax, 32));
    const float mnew = fmaxf(mrun, tmax);
    const float corr = __expf(mrun - mnew);
    float psum = 0.f;
#pragma unroll
    for (int i = 0; i < 8; i++) { p[i] = __expf(p[i] - mnew); psum += p[i]; }
    psum += __shfl_xor(psum, 16);
    psum += __shfl_xor(psum, 32);
    lrun = lrun * corr + psum;
    mrun = mnew;
#pragma unroll
    for (int i = 0; i < 4; i++)
#pragma unroll
      for (int rr = 0; rr < 4; rr++) acc[i][rr] *= corr;

    // P^T B-fragment: element e <-> kv = g*4 + (e&3) + 16*(e>>2)  (= D reg rows)
    union { half8 v; half_t e[8]; } pu;
#pragma unroll
    for (int i = 0; i < 8; i++) pu.e[i] = (half_t)p[i];

    // PV: O^T[d][q] += V^T * P^T
#pragma unroll
    for (int dt = 0; dt < 4; dt++) {
      union { half8 v; half_t e[8]; } vu;
#pragma unroll
      for (int e8 = 0; e8 < 8; e8++) {
        const int kvr = kv0 + g * 4 + (e8 & 3) + ((e8 >> 2) << 4);
        vu.e[e8] = Vp[(size_t)kvr * 64 + dt * 16 + r16];
      }
      acc[dt] = __builtin_amdgcn_mfma_f32_16x16x32_f16(vu.v, pu.v, acc[dt], 0, 0, 0);
    }
  }

  const float inv = 1.f / lrun;
  half_t* orow = O + ((size_t)b * 1024 + q0 + r16) * 512 + h * 64;
#pragma unroll
  for (int dt = 0; dt < 4; dt++)
#pragma unroll
    for (int rr = 0; rr < 4; rr++)
      orow[dt * 16 + g * 4 + rr] = (half_t)(acc[dt][rr] * inv);
}

extern "C" void kernel_launch(void* const* d_in, const int* in_sizes, int n_in,
                              void* d_out, int out_size, void* d_ws, size_t ws_size,
                              hipStream_t stream) {
  if (ws_size < 44040192u) return;  // need ~42 MB scratch
  const float* x  = (const float*)d_in[0];
  const float* Wq = (const float*)d_in[1];
  const float* bq = (const float*)d_in[2];
  const float* Wk = (const float*)d_in[3];
  const float* bk = (const float*)d_in[4];
  const float* Wv = (const float*)d_in[5];
  const float* bv = (const float*)d_in[6];
  const float* Wo = (const float*)d_in[7];
  const float* bo = (const float*)d_in[8];
  char* ws = (char*)d_ws;
  half_t* xr = (half_t*)(ws + 0);          // 8  MB: xr [8][1024][512] f16
  half_t* W4 = (half_t*)(ws + 8388608);    // 2  MB: Wq,Wk,Wv,Wo f16
  half_t* Qb = (half_t*)(ws + 10485760);   // 24 MB: Q,K,V [b][h][1024][64] f16
  half_t* AO = (half_t*)(ws + 35651584);   // 8  MB: attn out [b][s][512] f16
  float* out = (float*)d_out;

  prep_x_kernel<<<dim3(32, 16, 8), dim3(32, 8), 0, stream>>>(x, xr);
  prep_w_kernel<<<dim3(256, 4), 256, 0, stream>>>(Wq, Wk, Wv, Wo, W4);
  gemm_kernel<0><<<dim3(4, 64, 3), 256, 0, stream>>>(xr, W4, bq, bk, bv, Qb, nullptr);
  attn_kernel<<<dim3(1024), 256, 0, stream>>>(Qb, Qb + 4194304, Qb + 8388608, AO);
  gemm_kernel<1><<<dim3(4, 64, 1), 256, 0, stream>>>(AO, W4 + 786432, bo, nullptr, nullptr,
                                                     nullptr, out);
}